// Round 1
// baseline (302.206 us; speedup 1.0000x reference)
//
#include <hip/hip_runtime.h>

// Problem constants (fixed by setup_inputs)
#define Bsz 512
#define Tsz 12
#define Dsz 1024
#define Osz 512

// Tile config
#define BM 96     // 8 batches x 12 timesteps (contiguous rows of flattened (B*T, D))
#define BN 64
#define BK 32
#define NTH 192   // 12 ty-groups x 16 tx; each thread computes 8 rows x 4 cols

#define AST 100   // As_T row stride in floats (96 + 4 pad: keeps 16B align, breaks bank collisions)
#define WST 68    // Ws_T row stride in floats (64 + 4 pad)
#define BUFST 65  // reshuffle row stride in doubles

#define A_BYTES (BK * AST * 4)            // 12800
#define W_BYTES (BK * WST * 4)            // 8704
#define BUF_BYTES (BM * BUFST * 8)        // 49920
#define SMEM_BYTES BUF_BYTES              // union: max(staging 21504, buf 49920)

__global__ __launch_bounds__(NTH) void snn_fused(
    const float* __restrict__ x,      // (B, T, D) = flat (B*T, D)
    const float* __restrict__ Wm,     // (O, D)
    const float* __restrict__ bias,   // (O)
    float* __restrict__ out)          // (B, O)
{
    __shared__ __align__(16) char smem[SMEM_BYTES];
    float*  AsT = reinterpret_cast<float*>(smem);             // [BK][AST]
    float*  WsT = reinterpret_cast<float*>(smem + A_BYTES);   // [BK][WST]
    double* buf = reinterpret_cast<double*>(smem);            // [BM][BUFST] (reused after GEMM)

    const int tid = threadIdx.x;
    const int ty  = tid >> 4;   // 0..11 -> rows ty*8 .. ty*8+7
    const int tx  = tid & 15;   // 0..15 -> cols tx*4 .. tx*4+3

    const int n0 = blockIdx.x * BN;   // output-feature tile base
    const int b0 = blockIdx.y * 8;    // batch tile base (8 batches)
    const int r0 = b0 * Tsz;          // first row of flattened A

    double acc[8][4];
#pragma unroll
    for (int i = 0; i < 8; ++i)
#pragma unroll
        for (int j = 0; j < 4; ++j) acc[i][j] = 0.0;

    const float* Abase = x  + (size_t)r0 * Dsz;
    const float* Wbase = Wm + (size_t)n0 * Dsz;

    for (int k0 = 0; k0 < Dsz; k0 += BK) {
        __syncthreads();
        // ---- stage A tile (96 rows x 32 k) transposed into AsT[k][row] ----
#pragma unroll
        for (int it = 0; it < 4; ++it) {
            int idx = tid + NTH * it;          // 0..767
            int row = idx >> 3;
            int c4  = idx & 7;
            float4 v = *reinterpret_cast<const float4*>(Abase + (size_t)row * Dsz + k0 + c4 * 4);
            int kb = c4 * 4;
            AsT[(kb + 0) * AST + row] = v.x;
            AsT[(kb + 1) * AST + row] = v.y;
            AsT[(kb + 2) * AST + row] = v.z;
            AsT[(kb + 3) * AST + row] = v.w;
        }
        // ---- stage W tile (64 rows x 32 k) transposed into WsT[k][row] ----
#pragma unroll
        for (int it = 0; it < 3; ++it) {
            int idx = tid + NTH * it;          // need 0..511
            if (idx < 512) {
                int row = idx >> 3;
                int c4  = idx & 7;
                float4 v = *reinterpret_cast<const float4*>(Wbase + (size_t)row * Dsz + k0 + c4 * 4);
                int kb = c4 * 4;
                WsT[(kb + 0) * WST + row] = v.x;
                WsT[(kb + 1) * WST + row] = v.y;
                WsT[(kb + 2) * WST + row] = v.z;
                WsT[(kb + 3) * WST + row] = v.w;
            }
        }
        __syncthreads();

        // ---- inner product: fp64 accumulate ----
#pragma unroll 4
        for (int kk = 0; kk < BK; ++kk) {
            const float* ar = &AsT[kk * AST + ty * 8];
            float4 a0 = *reinterpret_cast<const float4*>(ar);
            float4 a1 = *reinterpret_cast<const float4*>(ar + 4);
            float4 w0 = *reinterpret_cast<const float4*>(&WsT[kk * WST + tx * 4]);
            double ad[8] = {(double)a0.x, (double)a0.y, (double)a0.z, (double)a0.w,
                            (double)a1.x, (double)a1.y, (double)a1.z, (double)a1.w};
            double wd[4] = {(double)w0.x, (double)w0.y, (double)w0.z, (double)w0.w};
#pragma unroll
            for (int i = 0; i < 8; ++i)
#pragma unroll
                for (int j = 0; j < 4; ++j)
                    acc[i][j] = fma(ad[i], wd[j], acc[i][j]);
        }
    }

    // ---- reshuffle accumulators into LDS so one thread owns all 12 t's of a (b,o) pair ----
    __syncthreads();
#pragma unroll
    for (int i = 0; i < 8; ++i)
#pragma unroll
        for (int j = 0; j < 4; ++j)
            buf[(ty * 8 + i) * BUFST + (tx * 4 + j)] = acc[i][j];
    __syncthreads();

    // ---- SNN dynamics: 8 batches x 64 outputs = 512 pairs ----
    for (int idx = tid; idx < 8 * BN; idx += NTH) {
        int bl = idx >> 6;    // 0..7 local batch
        int ol = idx & 63;    // 0..63 local output
        double bv = (double)bias[n0 + ol];
        double la[Tsz];
#pragma unroll
        for (int t = 0; t < Tsz; ++t)
            la[t] = buf[(bl * Tsz + t) * BUFST + ol] + bv;

        double v = 0.0, s = 0.0;
        float cnt = 0.0f;
        for (int oi = 0; oi < Tsz; ++oi) {   // outer scan: time_window = 12
            double c = 0.0;
#pragma unroll
            for (int t = 0; t < Tsz; ++t) {
                v = v * 0.2 * (1.0 - s) + la[t];   // leaky integrate with reset
                s = (v > 0.5) ? 1.0 : 0.0;          // fire
                c += s;
            }
            cnt = (float)c;   // keep last outer iteration's sum
        }
        out[(size_t)(b0 + bl) * Osz + (n0 + ol)] = cnt;
    }
}

extern "C" void kernel_launch(void* const* d_in, const int* in_sizes, int n_in,
                              void* d_out, int out_size, void* d_ws, size_t ws_size,
                              hipStream_t stream) {
    const float* x    = (const float*)d_in[0];   // (512,12,1024) fp32
    const float* Wm   = (const float*)d_in[1];   // (512,1024) fp32
    const float* bias = (const float*)d_in[2];   // (512) fp32
    // d_in[3] = time_window (=12), compile-time constant here
    float* out = (float*)d_out;                  // (512,512) fp32

    dim3 grid(Osz / BN, Bsz / 8);   // (8, 64) = 512 blocks
    dim3 block(NTH);
    hipLaunchKernelGGL(snn_fused, grid, block, 0, stream, x, Wm, bias, out);
}

// Round 3
// 251.379 us; speedup vs baseline: 1.2022x; 1.2022x over previous
//
#include <hip/hip_runtime.h>

// Problem constants (fixed by setup_inputs)
#define Bsz 512
#define Tsz 12
#define Dsz 1024
#define Osz 512

// Tile config: BM=48 rows (4 batches x 12 t), BN=64 outputs, BK=32
#define NB 4
#define BM (NB * Tsz)   // 48
#define BN 64
#define BK 32
#define NTH 192         // 12 ty-groups x 16 tx; 4x4 accumulators per thread

#define AST 52          // AsT row stride (floats): 48+4, keeps float4 align; reads conflict-free
#define WST 68          // WsT row stride (floats): 64+4
#define BUFST 64        // lin buffer row stride (floats)

#define A_FLOATS (BK * AST)      // 1664
#define W_FLOATS (BK * WST)      // 2176
// LDS layout (bytes):
//   GEMM phase:   AsT @0 (6656), WsT @6656 (8704)            -> 15360
//   post phase:   buf  @0 (48*64*4 = 12288)
//                 laL  @12288 (12*96*8 = 9216)   [fix-phase la staging]
//                 lcnt @21504 (4)
//                 list @21508 (256*4 = 1024)     -> total 22532
#define SMEM_BYTES 22536

#define MARGIN 5e-4     // conservative: worst-case fp32-GEMM error bound ~5e-5, x1.25 dynamics gain
#define FIXR 96         // flagged pairs processed per round

__global__ __launch_bounds__(NTH, 3) void snn_fused(
    const float* __restrict__ x,      // (B, T, D)
    const float* __restrict__ Wm,     // (O, D)
    const float* __restrict__ bias,   // (O)
    float* __restrict__ out)          // (B, O)
{
    __shared__ __align__(16) char smem[SMEM_BYTES];
    float*  AsT  = reinterpret_cast<float*>(smem);
    float*  WsT  = reinterpret_cast<float*>(smem + A_FLOATS * 4);
    float*  buf  = reinterpret_cast<float*>(smem);
    double* laL  = reinterpret_cast<double*>(smem + 12288);
    int*    lcnt = reinterpret_cast<int*>(smem + 21504);
    int*    list = reinterpret_cast<int*>(smem + 21508);

    const int tid = threadIdx.x;
    const int ty  = tid >> 4;   // 0..11 -> rows ty*4 .. ty*4+3
    const int tx  = tid & 15;   // 0..15 -> cols tx*4 .. tx*4+3

    const int n0 = blockIdx.x * BN;   // output-feature tile base
    const int b0 = blockIdx.y * NB;   // batch tile base
    const int r0 = b0 * Tsz;          // first row of flattened A

    float  acc[4][4];
    double acc64[4][4];
#pragma unroll
    for (int i = 0; i < 4; ++i)
#pragma unroll
        for (int j = 0; j < 4; ++j) { acc[i][j] = 0.0f; acc64[i][j] = 0.0; }

    const float* Ab = x  + (size_t)r0 * Dsz;
    const float* Wb = Wm + (size_t)n0 * Dsz;

    // ================= fp32 GEMM with chunked fp64 promotion =================
    for (int k0 = 0; k0 < Dsz; k0 += BK) {
        __syncthreads();
        // stage A tile (48 rows x 32 k) transposed: AsT[k][row]
#pragma unroll
        for (int it = 0; it < 2; ++it) {
            int idx = tid + NTH * it;          // 0..383
            int row = idx >> 3;
            int c4  = idx & 7;
            float4 v = *reinterpret_cast<const float4*>(Ab + (size_t)row * Dsz + k0 + c4 * 4);
            int kb = c4 * 4;
            AsT[(kb + 0) * AST + row] = v.x;
            AsT[(kb + 1) * AST + row] = v.y;
            AsT[(kb + 2) * AST + row] = v.z;
            AsT[(kb + 3) * AST + row] = v.w;
        }
        // stage W tile (64 rows x 32 k) transposed: WsT[k][row]
#pragma unroll
        for (int it = 0; it < 3; ++it) {
            int idx = tid + NTH * it;
            if (idx < 512) {
                int row = idx >> 3;
                int c4  = idx & 7;
                float4 v = *reinterpret_cast<const float4*>(Wb + (size_t)row * Dsz + k0 + c4 * 4);
                int kb = c4 * 4;
                WsT[(kb + 0) * WST + row] = v.x;
                WsT[(kb + 1) * WST + row] = v.y;
                WsT[(kb + 2) * WST + row] = v.z;
                WsT[(kb + 3) * WST + row] = v.w;
            }
        }
        __syncthreads();

#pragma unroll
        for (int kk = 0; kk < BK; ++kk) {
            float4 a = *reinterpret_cast<const float4*>(&AsT[kk * AST + ty * 4]);
            float4 w = *reinterpret_cast<const float4*>(&WsT[kk * WST + tx * 4]);
            acc[0][0] = fmaf(a.x, w.x, acc[0][0]);
            acc[0][1] = fmaf(a.x, w.y, acc[0][1]);
            acc[0][2] = fmaf(a.x, w.z, acc[0][2]);
            acc[0][3] = fmaf(a.x, w.w, acc[0][3]);
            acc[1][0] = fmaf(a.y, w.x, acc[1][0]);
            acc[1][1] = fmaf(a.y, w.y, acc[1][1]);
            acc[1][2] = fmaf(a.y, w.z, acc[1][2]);
            acc[1][3] = fmaf(a.y, w.w, acc[1][3]);
            acc[2][0] = fmaf(a.z, w.x, acc[2][0]);
            acc[2][1] = fmaf(a.z, w.y, acc[2][1]);
            acc[2][2] = fmaf(a.z, w.z, acc[2][2]);
            acc[2][3] = fmaf(a.z, w.w, acc[2][3]);
            acc[3][0] = fmaf(a.w, w.x, acc[3][0]);
            acc[3][1] = fmaf(a.w, w.y, acc[3][1]);
            acc[3][2] = fmaf(a.w, w.z, acc[3][2]);
            acc[3][3] = fmaf(a.w, w.w, acc[3][3]);
        }
        // promote fp32 chunk (64 k) into fp64 accumulator
        if (k0 & BK) {
#pragma unroll
            for (int i = 0; i < 4; ++i)
#pragma unroll
                for (int j = 0; j < 4; ++j) {
                    acc64[i][j] += (double)acc[i][j];
                    acc[i][j] = 0.0f;
                }
        }
    }

    // ================= reshuffle lin (fp32) into LDS =================
    __syncthreads();
#pragma unroll
    for (int i = 0; i < 4; ++i) {
        float4 o;
        o.x = (float)acc64[i][0];
        o.y = (float)acc64[i][1];
        o.z = (float)acc64[i][2];
        o.w = (float)acc64[i][3];
        *reinterpret_cast<float4*>(&buf[(ty * 4 + i) * BUFST + tx * 4]) = o;
    }
    if (tid == 0) *lcnt = 0;
    __syncthreads();

    // ================= dynamics (fp64 state, fp32 lin) + margin flagging =================
    for (int p = tid; p < NB * BN; p += NTH) {
        int bl = p >> 6;
        int ol = p & 63;
        double bv = (double)bias[n0 + ol];
        double la[Tsz];
#pragma unroll
        for (int t = 0; t < Tsz; ++t)
            la[t] = (double)buf[(bl * Tsz + t) * BUFST + ol] + bv;

        double v = 0.0, s = 0.0, minm = 1e30;
        float cf = 0.0f;
        for (int oi = 0; oi < Tsz; ++oi) {
            double c = 0.0;
#pragma unroll
            for (int t = 0; t < Tsz; ++t) {
                v = v * 0.2 * (1.0 - s) + la[t];
                double m = fabs(v - 0.5);
                minm = fmin(minm, m);
                s = (v > 0.5) ? 1.0 : 0.0;
                c += s;
            }
            cf = (float)c;
        }
        out[(size_t)(b0 + bl) * Osz + (n0 + ol)] = cf;
        if (minm < MARGIN) {
            int sl = atomicAdd(lcnt, 1);
            list[sl] = p;   // capacity 256 == max pairs/block, cannot overflow
        }
    }
    __syncthreads();

    // ================= exact fp64 recompute for flagged pairs =================
    int cnt = *lcnt;
    const int g   = tid >> 4;   // 16-lane group id, 0..11
    const int l16 = tid & 15;

    for (int base = 0; base < cnt; base += FIXR) {
        int rcnt = min(cnt - base, FIXR);
        // phase A: 16-lane-group fp64 dot products -> laL
        for (int i = g; i < rcnt; i += 12) {
            int p  = list[base + i];
            int bl = p >> 6;
            int ol = p & 63;
            const float* xr = x  + ((size_t)(b0 + bl) * Tsz) * Dsz + l16 * 64;
            const float* wr = Wm + (size_t)(n0 + ol) * Dsz + l16 * 64;
            double dot[Tsz];
#pragma unroll
            for (int t = 0; t < Tsz; ++t) dot[t] = 0.0;
            for (int c = 0; c < 16; ++c) {
                float4 w4 = *reinterpret_cast<const float4*>(wr + c * 4);
                double w0 = (double)w4.x, w1 = (double)w4.y, w2 = (double)w4.z, w3 = (double)w4.w;
#pragma unroll
                for (int t = 0; t < Tsz; ++t) {
                    float4 x4 = *reinterpret_cast<const float4*>(xr + (size_t)t * Dsz + c * 4);
                    double d = dot[t];
                    d = fma((double)x4.x, w0, d);
                    d = fma((double)x4.y, w1, d);
                    d = fma((double)x4.z, w2, d);
                    d = fma((double)x4.w, w3, d);
                    dot[t] = d;
                }
            }
#pragma unroll
            for (int off = 8; off; off >>= 1)
#pragma unroll
                for (int t = 0; t < Tsz; ++t)
                    dot[t] += __shfl_down(dot[t], off, 16);
            if (l16 == 0) {
                double bv = (double)bias[n0 + ol];
#pragma unroll
                for (int t = 0; t < Tsz; ++t)
                    laL[t * FIXR + i] = dot[t] + bv;
            }
        }
        __syncthreads();
        // phase B: thread-per-pair exact fp64 dynamics
        if (tid < rcnt) {
            int p  = list[base + tid];
            int bl = p >> 6;
            int ol = p & 63;
            double la[Tsz];
#pragma unroll
            for (int t = 0; t < Tsz; ++t) la[t] = laL[t * FIXR + tid];
            double v = 0.0, s = 0.0, c = 0.0;
            for (int oi = 0; oi < Tsz; ++oi) {
                c = 0.0;
#pragma unroll
                for (int t = 0; t < Tsz; ++t) {
                    v = v * 0.2 * (1.0 - s) + la[t];
                    s = (v > 0.5) ? 1.0 : 0.0;
                    c += s;
                }
            }
            out[(size_t)(b0 + bl) * Osz + (n0 + ol)] = (float)c;
        }
        __syncthreads();
    }
}

extern "C" void kernel_launch(void* const* d_in, const int* in_sizes, int n_in,
                              void* d_out, int out_size, void* d_ws, size_t ws_size,
                              hipStream_t stream) {
    const float* x    = (const float*)d_in[0];   // (512,12,1024) fp32
    const float* Wm   = (const float*)d_in[1];   // (512,1024) fp32
    const float* bias = (const float*)d_in[2];   // (512) fp32
    float* out = (float*)d_out;                  // (512,512) fp32

    dim3 grid(Osz / BN, Bsz / NB);   // (8, 128) = 1024 blocks
    dim3 block(NTH);
    hipLaunchKernelGGL(snn_fused, grid, block, 0, stream, x, Wm, bias, out);
}